// Round 10
// baseline (751.073 us; speedup 1.0000x reference)
//
#include <hip/hip_runtime.h>
#include <math.h>

#define EMB 64
static constexpr float INV_SQRT_DK = 0.17677669529663687f; // 1/sqrt(32)

#define NPART 32          // node-range partitions for the bucket sort
#define NBK 512           // KG bucket blocks
#define NBU 192           // UI bucket blocks
#define P3_PROJ 1024      // proj-role blocks appended to p3 (streaming || streaming)
#define P4_KG 1024        // KG scatter blocks (32 slices x 32 partitions)
#define P4_UI 512         // UI scatter blocks (16 slices x 32 partitions)

typedef unsigned uint2v __attribute__((ext_vector_type(2)));

__device__ inline unsigned short f2bf(float f) {
    union { float f; unsigned u; } v; v.f = f;
    unsigned r = v.u + 0x7FFF + ((v.u >> 16) & 1);   // round-to-nearest-even
    return (unsigned short)(r >> 16);
}
__device__ inline float bfhi(unsigned w) {           // high 16 bits as bf16
    union { float f; unsigned u; } v; v.u = w & 0xFFFF0000u; return v.f;
}
__device__ inline float bflo(unsigned w) {           // low 16 bits as bf16
    union { float f; unsigned u; } v; v.u = w << 16; return v.f;
}

// ---- proj rows: packed[r] = (bf16(e@W) << 16) | bf16(e), grid-stride ----
__device__ inline void proj_rows(const float* __restrict__ e, const float* __restrict__ Wl,
                                 unsigned* __restrict__ packed, int n, int wid, int nw, int lane) {
    for (int r = wid; r < n; r += nw) {
        float x = e[(size_t)r * EMB + lane];
        float acc = 0.f;
#pragma unroll
        for (int k = 0; k < 64; ++k) {
            float ek = __shfl(x, k, 64);
            acc += ek * Wl[k * 64 + lane];
        }
        packed[(size_t)r * EMB + lane] = (((unsigned)f2bf(acc)) << 16) | f2bf(x);
    }
}

// ---------------- P1: per-node histogram only ----------------
__global__ void p1_hist(const int* __restrict__ head, int* __restrict__ cnt_h, int E,
                        const int* __restrict__ iu, int* __restrict__ cnt_u, int EI) {
    int i = blockIdx.x * blockDim.x + threadIdx.x;
    if (i < E) atomicAdd(&cnt_h[__builtin_nontemporal_load(&head[i])], 1);
    else if (i < E + EI) atomicAdd(&cnt_u[__builtin_nontemporal_load(&iu[i - E])], 1);
}

// ---------------- multi-block exclusive scan of node degrees (3 phases) ----------------
__global__ void scan_partial_both(const int* __restrict__ degH, int* __restrict__ partH,
                                  int nH, int nbH,
                                  const int* __restrict__ degU, int* __restrict__ partU, int nU) {
    bool isU = (int)blockIdx.x >= nbH;
    const int* deg = isU ? degU : degH;
    int* part = isU ? partU : partH;
    int n = isU ? nU : nH;
    int b = isU ? blockIdx.x - nbH : blockIdx.x;
    int t = threadIdx.x;             // 256 threads, 4 elems each
    int i0 = b * 1024 + t * 4;
    int s = 0;
#pragma unroll
    for (int k = 0; k < 4; ++k) { int id = i0 + k; if (id < n) s += deg[id]; }
#pragma unroll
    for (int m = 1; m <= 32; m <<= 1) s += __shfl_xor(s, m, 64);
    __shared__ int wsum[4];
    if ((t & 63) == 0) wsum[t >> 6] = s;
    __syncthreads();
    if (t == 0) part[b] = wsum[0] + wsum[1] + wsum[2] + wsum[3];
}

__global__ void scan_block_both(int* __restrict__ partH, int nbH,
                                int* __restrict__ partU, int nbU) {
    __shared__ int sh[256];
    int t = threadIdx.x;
    for (int pass = 0; pass < 2; ++pass) {
        int* part = pass ? partU : partH;
        int nb = pass ? nbU : nbH;
        int v = (t < nb) ? part[t] : 0;
        sh[t] = v;
        __syncthreads();
        for (int d = 1; d < 256; d <<= 1) {
            int x = (t >= d) ? sh[t - d] : 0;
            __syncthreads();
            sh[t] += x;
            __syncthreads();
        }
        if (t < nb) part[t] = sh[t] - v; // exclusive
        __syncthreads();
    }
}

// writes both off[] and cur[] (fill cursor)
__global__ void scan_final_both(const int* __restrict__ degH, const int* __restrict__ partH,
                                int* __restrict__ offH, int* __restrict__ curH,
                                int nH, int nbH, int totalH,
                                const int* __restrict__ degU, const int* __restrict__ partU,
                                int* __restrict__ offU, int* __restrict__ curU,
                                int nU, int totalU) {
    bool isU = (int)blockIdx.x >= nbH;
    const int* deg = isU ? degU : degH;
    const int* part = isU ? partU : partH;
    int* off = isU ? offU : offH;
    int* cur = isU ? curU : curH;
    int n = isU ? nU : nH;
    int total = isU ? totalU : totalH;
    int b = isU ? blockIdx.x - nbH : blockIdx.x;
    int t = threadIdx.x;
    int lane = t & 63, w = t >> 6;
    int i0 = b * 1024 + t * 4;
    int v[4]; int s = 0;
#pragma unroll
    for (int k = 0; k < 4; ++k) { int id = i0 + k; v[k] = (id < n) ? deg[id] : 0; s += v[k]; }
    int incl = s;
#pragma unroll
    for (int d = 1; d < 64; d <<= 1) { int x = __shfl_up(incl, d, 64); if (lane >= d) incl += x; }
    __shared__ int wsum[4];
    if (lane == 63) wsum[w] = incl;
    __syncthreads();
    int woff = 0;
    for (int i = 0; i < w; ++i) woff += wsum[i];
    int excl = incl - s + woff + part[b];
#pragma unroll
    for (int k = 0; k < 4; ++k) {
        int id = i0 + k;
        if (id < n) { off[id] = excl; cur[id] = excl; }
        excl += v[k];
    }
    if (b == 0 && t == 0) off[n] = total;
}

// ---------------- partition base cursors from off[] ----------------
__global__ void pcur_init(const int* __restrict__ off_h, int n_ent, int shiftH,
                          int* __restrict__ pcurK,
                          const int* __restrict__ off_u, int n_usr, int shiftU,
                          int* __restrict__ pcurU) {
    int t = threadIdx.x;
    if (t < NPART) {
        pcurK[t] = off_h[min(t << shiftH, n_ent)];
        pcurU[t] = off_u[min(t << shiftU, n_usr)];
    }
}

// ---- P3: self-reserving dense bucket write  MERGED with hop-1 proj (both streaming) ----
__global__ void __launch_bounds__(256) p3proj_kernel(
        const int* __restrict__ head, const int* __restrict__ tail,
        const int* __restrict__ etype, int E, int shiftH,
        int* __restrict__ pcurK, uint2v* __restrict__ bktK,
        const int* __restrict__ iu, const int* __restrict__ ii,
        const float* __restrict__ w, int EI, int shiftU,
        int* __restrict__ pcurU, uint2v* __restrict__ bktU,
        const float* __restrict__ e_in, const float* __restrict__ W,
        unsigned* __restrict__ packed, int n_ent) {
    __shared__ float sh[64 * 64];
    int b = blockIdx.x;
    if (b >= NBK + NBU) {
        // ---- proj role: grid-stride over entity rows ----
        for (int i = threadIdx.x; i < 64 * 64; i += 256) sh[i] = W[i];
        __syncthreads();
        int lane = threadIdx.x & 63;
        int wid = (b - (NBK + NBU)) * 4 + (threadIdx.x >> 6);
        proj_rows(e_in, sh, packed, n_ent, wid, P3_PROJ * 4, lane);
        return;
    }
    int* lc = (int*)sh;
    if (threadIdx.x < NPART) lc[threadIdx.x] = 0;
    __syncthreads();
    if (b < NBK) {
        int chunk = (E + NBK - 1) / NBK;
        int lo = b * chunk, hi = min(lo + chunk, E);
        for (int e = lo + (int)threadIdx.x; e < hi; e += 256)
            atomicAdd(&lc[__builtin_nontemporal_load(&head[e]) >> shiftH], 1);
        __syncthreads();
        if (threadIdx.x < NPART)
            lc[threadIdx.x] = atomicAdd(&pcurK[threadIdx.x], lc[threadIdx.x]);
        __syncthreads();
        for (int e = lo + (int)threadIdx.x; e < hi; e += 256) {
            int h = __builtin_nontemporal_load(&head[e]);
            int tl = __builtin_nontemporal_load(&tail[e]);
            int ty = __builtin_nontemporal_load(&etype[e]);
            int pos = atomicAdd(&lc[h >> shiftH], 1);
            uint2v r; r.x = (unsigned)(tl | ((ty - 1) << 17)); r.y = (unsigned)h;
            __builtin_nontemporal_store(r, &bktK[pos]);
        }
    } else {
        int bb = b - NBK;
        int chunk = (EI + NBU - 1) / NBU;
        int lo = bb * chunk, hi = min(lo + chunk, EI);
        for (int e = lo + (int)threadIdx.x; e < hi; e += 256)
            atomicAdd(&lc[__builtin_nontemporal_load(&iu[e]) >> shiftU], 1);
        __syncthreads();
        if (threadIdx.x < NPART)
            lc[threadIdx.x] = atomicAdd(&pcurU[threadIdx.x], lc[threadIdx.x]);
        __syncthreads();
        for (int e = lo + (int)threadIdx.x; e < hi; e += 256) {
            int u = __builtin_nontemporal_load(&iu[e]);
            int it = __builtin_nontemporal_load(&ii[e]);
            float wv = __builtin_nontemporal_load(&w[e]);
            int pos = atomicAdd(&lc[u >> shiftU], 1);
            unsigned wq = (unsigned)(wv * 32767.f + 0.5f);
            uint2v r; r.x = (unsigned)it | (wq << 17); r.y = (unsigned)u;
            __builtin_nontemporal_store(r, &bktU[pos]);
        }
    }
}

// ---------------- P4: pure partition-local scatter into CSR col ----------------
// partition p = blockIdx % 32 keeps writes XCD-local; nontemporal bucket reads keep
// the read-once stream from evicting the L2-resident col write-set.
__global__ void __launch_bounds__(256) p4_fill_kernel(
        const uint2v* __restrict__ bktK, const int* __restrict__ off_h, int n_ent, int shiftH,
        int* __restrict__ cur_h, int* __restrict__ col_h,
        const uint2v* __restrict__ bktU, const int* __restrict__ off_u, int n_usr, int shiftU,
        int* __restrict__ cur_u, unsigned* __restrict__ col_ui) {
    int b = blockIdx.x;
    if (b < P4_KG) {
        int p = b & (NPART - 1), s = b >> 5;            // 32 slices per partition
        int st = off_h[min(p << shiftH, n_ent)];
        int en = off_h[min((p + 1) << shiftH, n_ent)];
        long long len = en - st;
        int lo = st + (int)(len * s / 32);
        int hi = st + (int)(len * (s + 1) / 32);
        for (int i = lo + (int)threadIdx.x; i < hi; i += 256) {
            uint2v r = __builtin_nontemporal_load(&bktK[i]);
            int pos = atomicAdd(&cur_h[r.y], 1);
            col_h[pos] = (int)r.x;
        }
    } else {
        int bb = b - P4_KG;
        int p = bb & (NPART - 1), s = bb >> 5;          // 16 slices per partition
        int st = off_u[min(p << shiftU, n_usr)];
        int en = off_u[min((p + 1) << shiftU, n_usr)];
        long long len = en - st;
        int lo = st + (int)(len * s / 16);
        int hi = st + (int)(len * (s + 1) / 16);
        for (int i = lo + (int)threadIdx.x; i < hi; i += 256) {
            uint2v r = __builtin_nontemporal_load(&bktU[i]);
            int pos = atomicAdd(&cur_u[r.y], 1);
            col_ui[pos] = r.x;
        }
    }
}

// ------- fused agg: KG = 2 dims/lane, 2 edges/wave;  UI = per-user weighted agg -------
// HOP1 additionally computes proj(e_norm) in-register (W in LDS) and emits packed2,
// deleting the separate hop-2 proj pass and the f32 e_cur buffer.
#define KG_PAIR(J, P, W) {                                                  \
        int rr = (P) >> 17;                                                 \
        float rl0 = relS[rr * EMB + dd], rl1 = relS[rr * EMB + dd + 1];     \
        float pt0 = bfhi(W.x), pt1 = bfhi(W.y);                             \
        float et0 = bflo(W.x), et1 = bflo(W.y);                             \
        float prod = fmaf(q0 * rl0, pt0, q1 * rl1 * pt1);                   \
        prod += __shfl_xor(prod, 1, 64);                                    \
        prod += __shfl_xor(prod, 2, 64);                                    \
        prod += __shfl_xor(prod, 4, 64);                                    \
        prod += __shfl_xor(prod, 8, 64);                                    \
        float ex = __expf(prod * INV_SQRT_DK);                              \
        if ((J) + half >= e) ex = 0.f;                                      \
        den += ex;                                                          \
        num0 = fmaf(ex * rl0, et0, num0);                                   \
        num1 = fmaf(ex * rl1, et1, num1); }

template <bool HOP1>
__global__ void __launch_bounds__(256) agg_fused_kernel(
        const unsigned* __restrict__ pk,          // gather table for this hop
        unsigned* __restrict__ pk_out,            // HOP1: packed table for next hop
        const float* __restrict__ W,              // HOP1 only
        const float* __restrict__ rel_emb,
        const int* __restrict__ off_h, const int* __restrict__ col_h,
        const int* __restrict__ off_u, const unsigned* __restrict__ col_ui,
        const float* __restrict__ e_base, float* __restrict__ e_res, int n_ent,
        const float* __restrict__ u_base, float* __restrict__ u_res,
        int n_usr, int kgBlocks, int totalBlocks) {
    __shared__ float sh[HOP1 ? (16 * EMB + 64 * 64) : 16 * EMB];   // relS [+ W]
    float* relS = sh;
    float* Wl = sh + 16 * EMB;
    int bid = blockIdx.x;
    // Bresenham interleave of kg-role and ui-role blocks
    size_t lo = (size_t)bid * kgBlocks / totalBlocks;
    size_t hi = (size_t)(bid + 1) * kgBlocks / totalBlocks;
    int lane = threadIdx.x & 63;
    int wslot = threadIdx.x >> 6;

    if (hi > lo) {
        // ---------------- KG entity block: 2 dims/lane, 2 edges/wave ----------------
        for (int i = threadIdx.x; i < 16 * EMB; i += blockDim.x) relS[i] = rel_emb[i];
        if (HOP1)
            for (int i = threadIdx.x; i < 64 * 64; i += blockDim.x) Wl[i] = W[i];
        __syncthreads();
        int wid = (int)lo * 4 + wslot;
        if (wid >= n_ent) return;
        int s = off_h[wid], e = off_h[wid + 1];
        int half = lane >> 5;
        int sub  = lane & 31;
        int dd   = sub * 2;
        uint2 qw = *(const uint2*)&pk[(size_t)wid * EMB + dd];
        float q0 = bfhi(qw.x), q1 = bfhi(qw.y);
        float num0 = 0.f, num1 = 0.f, den = 0.f;
        int j = s;
        for (; j + 3 < e; j += 4) {           // 2 pairs (4 edges), no dummies possible
            int pA = col_h[j + half];
            int pB = col_h[j + 2 + half];
            uint2 wA = *(const uint2*)&pk[(size_t)(pA & 131071) * EMB + dd];
            uint2 wB = *(const uint2*)&pk[(size_t)(pB & 131071) * EMB + dd];
            KG_PAIR(j, pA, wA);
            KG_PAIR(j + 2, pB, wB);
        }
        for (; j < e; j += 2) {               // remainder pair, may have a dummy lane-half
            int jj = j + half; if (jj >= e) jj = e - 1;
            int pA = col_h[jj];
            uint2 wA = *(const uint2*)&pk[(size_t)(pA & 131071) * EMB + dd];
            KG_PAIR(j, pA, wA);
        }
        // combine the two edge-halves (once per node); both halves end identical
        den  += __shfl_xor(den, 32, 64);
        num0 += __shfl_xor(num0, 32, 64);
        num1 += __shfl_xor(num1, 32, 64);
        float inv = (e > s) ? 1.f / den : 0.f;   // deferred softmax division
        float v0 = num0 * inv, v1 = num1 * inv;
        float ss = fmaf(v0, v0, v1 * v1);
#pragma unroll
        for (int m = 1; m <= 16; m <<= 1) ss += __shfl_xor(ss, m, 64);
        float rn = 1.f / fmaxf(sqrtf(ss), 1e-12f);
        float o0 = v0 * rn, o1 = v1 * rn;       // dims (2*sub, 2*sub+1), all 64 lanes
        // element belonging to THIS lane (dim = lane)
        float a0 = __shfl(o0, lane >> 1, 64);
        float a1 = __shfl(o1, lane >> 1, 64);
        float em = (lane & 1) ? a1 : a0;
        size_t ix = (size_t)wid * EMB + lane;
        if (HOP1) {
            // in-register proj of the normalized row against W (LDS)
            float accA = 0.f, accB = 0.f;
#pragma unroll
            for (int k = 0; k < 64; k += 2) {
                float eA = __shfl(o0, k >> 1, 64);
                float eB = __shfl(o1, k >> 1, 64);
                accA = fmaf(eA, Wl[k * 64 + lane], accA);
                accB = fmaf(eB, Wl[(k + 1) * 64 + lane], accB);
            }
            float pj = accA + accB;
            pk_out[ix] = (((unsigned)f2bf(pj)) << 16) | f2bf(em);
            e_res[ix] = e_base[ix] + em;
        } else {
            e_res[ix] += em;
        }
    } else {
        // ---------------- UI user block (values from bflo(pk)) ----------------
        int wid = (bid - (int)lo) * 4 + wslot;
        if (wid >= n_usr) return;
        int s = off_u[wid], e = off_u[wid + 1];
        float acc = 0.f;
        int j = s;
        for (; j + 3 < e; j += 4) {
            unsigned c0 = col_ui[j],     c1 = col_ui[j + 1];
            unsigned c2 = col_ui[j + 2], c3 = col_ui[j + 3];
            float w0 = (c0 >> 17) * (1.f / 32767.f);
            float w1 = (c1 >> 17) * (1.f / 32767.f);
            float w2 = (c2 >> 17) * (1.f / 32767.f);
            float w3 = (c3 >> 17) * (1.f / 32767.f);
            float v0 = bflo(pk[(size_t)(c0 & 131071u) * EMB + lane]);
            float v1 = bflo(pk[(size_t)(c1 & 131071u) * EMB + lane]);
            float v2 = bflo(pk[(size_t)(c2 & 131071u) * EMB + lane]);
            float v3 = bflo(pk[(size_t)(c3 & 131071u) * EMB + lane]);
            acc = fmaf(w0, v0, acc);
            acc = fmaf(w1, v1, acc);
            acc = fmaf(w2, v2, acc);
            acc = fmaf(w3, v3, acc);
        }
        for (; j < e; ++j) {
            unsigned c = col_ui[j];
            acc = fmaf((c >> 17) * (1.f / 32767.f),
                       bflo(pk[(size_t)(c & 131071u) * EMB + lane]), acc);
        }
        float ss = acc * acc;
#pragma unroll
        for (int m = 1; m <= 32; m <<= 1) ss += __shfl_xor(ss, m, 64);
        float o = acc / fmaxf(sqrtf(ss), 1e-12f);
        size_t ix = (size_t)wid * EMB + lane;
        if (HOP1) u_res[ix] = u_base[ix] + o;
        else      u_res[ix] += o;
    }
}

extern "C" void kernel_launch(void* const* d_in, const int* in_sizes, int n_in,
                              void* d_out, int out_size, void* d_ws, size_t ws_size,
                              hipStream_t stream) {
    const float* user_emb   = (const float*)d_in[0];
    const float* entity_emb = (const float*)d_in[1];
    const int*   edge_index = (const int*)d_in[2];   // [2, E]
    const int*   edge_type  = (const int*)d_in[3];   // [E]
    const int*   inter_edge = (const int*)d_in[4];   // [2, EI]
    const float* inter_w    = (const float*)d_in[5]; // [EI]
    const float* W_Q        = (const float*)d_in[6]; // [64,64]
    const float* rel_emb    = (const float*)d_in[7]; // [16,64]

    const int E     = in_sizes[3];
    const int EI    = in_sizes[5];
    const int n_ent = in_sizes[1] / EMB;
    const int n_usr = in_sizes[0] / EMB;

    const int* head = edge_index;
    const int* tail = edge_index + E;
    const int* iu   = inter_edge;
    const int* ii   = inter_edge + EI;

    // partition shifts: smallest shift with <= NPART partitions
    int shiftH = 0; while (((n_ent + (1 << shiftH) - 1) >> shiftH) > NPART) ++shiftH;
    int shiftU = 0; while (((n_usr + (1 << shiftU) - 1) >> shiftU) > NPART) ++shiftU;

    // ---- workspace layout ----
    char* ws = (char*)d_ws;
    unsigned* packed  = (unsigned*)ws;         ws += (size_t)n_ent * EMB * 4;   // hop-1 table
    unsigned* packed2 = (unsigned*)ws;         ws += (size_t)n_ent * EMB * 4;   // hop-2 table
    int*      col_h  = (int*)ws;               ws += (size_t)E * 4;
    unsigned* col_ui = (unsigned*)ws;          ws += (size_t)EI * 4;
    int*   off_h = (int*)ws;                   ws += (size_t)(n_ent + 1) * 4;
    int*   off_u = (int*)ws;                   ws += (size_t)(n_usr + 1) * 4;
    int*   cur_h = (int*)ws;                   ws += (size_t)n_ent * 4;   // cur_h|cur_u adjacent
    int*   cur_u = (int*)ws;                   ws += (size_t)n_usr * 4;
    int*   partH = (int*)ws;                   ws += 256 * 4;
    int*   partU = (int*)ws;                   ws += 256 * 4;
    int*   pcurK = (int*)ws;                   ws += NPART * 4;
    int*   pcurU = (int*)ws;                   ws += NPART * 4;
    // buckets overlay packed2 (dead until agg1 writes it, after p4 consumes buckets)
    uint2v* bktK = (uint2v*)packed2;           // E * 8 bytes
    uint2v* bktU = bktK + E;                   // EI * 8 bytes (24 MB <= 25.6 MB region)

    float* e_res = (float*)d_out;
    float* u_res = e_res + (size_t)n_ent * EMB;

    const int nbH = (n_ent + 1023) / 1024;     // 98  (<=256)
    const int nbU = (n_usr + 1023) / 1024;     // 49  (<=256)

    // ---- CSR build via partition counting-sort (reused by both hops) ----
    hipMemsetAsync(cur_h, 0, (size_t)(n_ent + n_usr) * 4, stream);
    p1_hist<<<(E + EI + 255) / 256, 256, 0, stream>>>(head, cur_h, E, iu, cur_u, EI);
    scan_partial_both<<<nbH + nbU, 256, 0, stream>>>(cur_h, partH, n_ent, nbH, cur_u, partU, n_usr);
    scan_block_both<<<1, 256, 0, stream>>>(partH, nbH, partU, nbU);
    scan_final_both<<<nbH + nbU, 256, 0, stream>>>(cur_h, partH, off_h, cur_h, n_ent, nbH, E,
                                                   cur_u, partU, off_u, cur_u, n_usr, EI);
    pcur_init<<<1, 64, 0, stream>>>(off_h, n_ent, shiftH, pcurK, off_u, n_usr, shiftU, pcurU);
    // bucket write merged with hop-1 proj (both streaming; no L2-resident set to disturb)
    p3proj_kernel<<<NBK + NBU + P3_PROJ, 256, 0, stream>>>(
        head, tail, edge_type, E, shiftH, pcurK, bktK,
        iu, ii, inter_w, EI, shiftU, pcurU, bktU,
        entity_emb, W_Q, packed, n_ent);
    // pure partition-local scatter (L2-resident col regions)
    p4_fill_kernel<<<P4_KG + P4_UI, 256, 0, stream>>>(
        bktK, off_h, n_ent, shiftH, cur_h, col_h,
        bktU, off_u, n_usr, shiftU, cur_u, col_ui);

    const int kgBlocks = (n_ent + 3) / 4;
    const int uiBlocks = (n_usr + 3) / 4;
    const int totalBlocks = kgBlocks + uiBlocks;

    // ---- hop 1 (table = packed; emits packed2 for hop 2 in-kernel) ----
    agg_fused_kernel<true><<<totalBlocks, 256, 0, stream>>>(
        packed, packed2, W_Q, rel_emb, off_h, col_h, off_u, col_ui,
        entity_emb, e_res, n_ent, user_emb, u_res, n_usr, kgBlocks, totalBlocks);

    // ---- hop 2 (table = packed2) ----
    agg_fused_kernel<false><<<totalBlocks, 256, 0, stream>>>(
        packed2, nullptr, nullptr, rel_emb, off_h, col_h, off_u, col_ui,
        nullptr, e_res, n_ent, nullptr, u_res, n_usr, kgBlocks, totalBlocks);
}

// Round 11
// 742.683 us; speedup vs baseline: 1.0113x; 1.0113x over previous
//
#include <hip/hip_runtime.h>
#include <math.h>

#define EMB 64
static constexpr float INV_SQRT_DK = 0.17677669529663687f; // 1/sqrt(32)

#define NPART 32          // node-range partitions for the bucket sort
#define NBK 512           // KG bucket blocks
#define NBU 192           // UI bucket blocks
#define P3_PROJ 1024      // proj-role blocks appended to p3 (streaming || streaming)
#define P4_KG 1024        // KG scatter blocks (32 slices x 32 partitions)
#define P4_UI 512         // UI scatter blocks (16 slices x 32 partitions)
#define PROJ2_BLOCKS 2048

typedef unsigned uint2v __attribute__((ext_vector_type(2)));

__device__ inline unsigned short f2bf(float f) {
    union { float f; unsigned u; } v; v.f = f;
    unsigned r = v.u + 0x7FFF + ((v.u >> 16) & 1);   // round-to-nearest-even
    return (unsigned short)(r >> 16);
}
__device__ inline float bfhi(unsigned w) {           // high 16 bits as bf16
    union { float f; unsigned u; } v; v.u = w & 0xFFFF0000u; return v.f;
}
__device__ inline float bflo(unsigned w) {           // low 16 bits as bf16
    union { float f; unsigned u; } v; v.u = w << 16; return v.f;
}
__device__ inline float bf2f(unsigned short b) {
    union { float f; unsigned u; } v; v.u = ((unsigned)b) << 16; return v.f;
}

// ---- hop-1 proj rows: packed[r] = (bf16(e@W) << 16) | bf16(e), grid-stride ----
__device__ inline void proj_rows(const float* __restrict__ e, const float* __restrict__ Wl,
                                 unsigned* __restrict__ packed, int n, int wid, int nw, int lane) {
    for (int r = wid; r < n; r += nw) {
        float x = e[(size_t)r * EMB + lane];
        float acc = 0.f;
#pragma unroll
        for (int k = 0; k < 64; ++k) {
            float ek = __shfl(x, k, 64);
            acc += ek * Wl[k * 64 + lane];
        }
        packed[(size_t)r * EMB + lane] = (((unsigned)f2bf(acc)) << 16) | f2bf(x);
    }
}

// ---- hop-2 proj from bf16 normalized rows (4x smaller input than f32) ----
__global__ void __launch_bounds__(256) proj2b_kernel(
        const unsigned short* __restrict__ enorm, const float* __restrict__ W,
        unsigned* __restrict__ packed2, int n) {
    __shared__ float Wl[64 * 64];
    for (int i = threadIdx.x; i < 64 * 64; i += 256) Wl[i] = W[i];
    __syncthreads();
    int lane = threadIdx.x & 63;
    int wid = blockIdx.x * 4 + (threadIdx.x >> 6);
    int nw = PROJ2_BLOCKS * 4;
    for (int r = wid; r < n; r += nw) {
        unsigned short eb = enorm[(size_t)r * EMB + lane];
        float x = bf2f(eb);
        float acc = 0.f;
#pragma unroll
        for (int k = 0; k < 64; ++k) {
            float ek = __shfl(x, k, 64);
            acc += ek * Wl[k * 64 + lane];
        }
        packed2[(size_t)r * EMB + lane] = (((unsigned)f2bf(acc)) << 16) | eb;
    }
}

// ---------------- P1: per-node histogram only ----------------
__global__ void p1_hist(const int* __restrict__ head, int* __restrict__ cnt_h, int E,
                        const int* __restrict__ iu, int* __restrict__ cnt_u, int EI) {
    int i = blockIdx.x * blockDim.x + threadIdx.x;
    if (i < E) atomicAdd(&cnt_h[__builtin_nontemporal_load(&head[i])], 1);
    else if (i < E + EI) atomicAdd(&cnt_u[__builtin_nontemporal_load(&iu[i - E])], 1);
}

// ---------------- multi-block exclusive scan of node degrees (3 phases) ----------------
__global__ void scan_partial_both(const int* __restrict__ degH, int* __restrict__ partH,
                                  int nH, int nbH,
                                  const int* __restrict__ degU, int* __restrict__ partU, int nU) {
    bool isU = (int)blockIdx.x >= nbH;
    const int* deg = isU ? degU : degH;
    int* part = isU ? partU : partH;
    int n = isU ? nU : nH;
    int b = isU ? blockIdx.x - nbH : blockIdx.x;
    int t = threadIdx.x;             // 256 threads, 4 elems each
    int i0 = b * 1024 + t * 4;
    int s = 0;
#pragma unroll
    for (int k = 0; k < 4; ++k) { int id = i0 + k; if (id < n) s += deg[id]; }
#pragma unroll
    for (int m = 1; m <= 32; m <<= 1) s += __shfl_xor(s, m, 64);
    __shared__ int wsum[4];
    if ((t & 63) == 0) wsum[t >> 6] = s;
    __syncthreads();
    if (t == 0) part[b] = wsum[0] + wsum[1] + wsum[2] + wsum[3];
}

__global__ void scan_block_both(int* __restrict__ partH, int nbH,
                                int* __restrict__ partU, int nbU) {
    __shared__ int sh[256];
    int t = threadIdx.x;
    for (int pass = 0; pass < 2; ++pass) {
        int* part = pass ? partU : partH;
        int nb = pass ? nbU : nbH;
        int v = (t < nb) ? part[t] : 0;
        sh[t] = v;
        __syncthreads();
        for (int d = 1; d < 256; d <<= 1) {
            int x = (t >= d) ? sh[t - d] : 0;
            __syncthreads();
            sh[t] += x;
            __syncthreads();
        }
        if (t < nb) part[t] = sh[t] - v; // exclusive
        __syncthreads();
    }
}

// writes both off[] and cur[] (fill cursor)
__global__ void scan_final_both(const int* __restrict__ degH, const int* __restrict__ partH,
                                int* __restrict__ offH, int* __restrict__ curH,
                                int nH, int nbH, int totalH,
                                const int* __restrict__ degU, const int* __restrict__ partU,
                                int* __restrict__ offU, int* __restrict__ curU,
                                int nU, int totalU) {
    bool isU = (int)blockIdx.x >= nbH;
    const int* deg = isU ? degU : degH;
    const int* part = isU ? partU : partH;
    int* off = isU ? offU : offH;
    int* cur = isU ? curU : curH;
    int n = isU ? nU : nH;
    int total = isU ? totalU : totalH;
    int b = isU ? blockIdx.x - nbH : blockIdx.x;
    int t = threadIdx.x;
    int lane = t & 63, w = t >> 6;
    int i0 = b * 1024 + t * 4;
    int v[4]; int s = 0;
#pragma unroll
    for (int k = 0; k < 4; ++k) { int id = i0 + k; v[k] = (id < n) ? deg[id] : 0; s += v[k]; }
    int incl = s;
#pragma unroll
    for (int d = 1; d < 64; d <<= 1) { int x = __shfl_up(incl, d, 64); if (lane >= d) incl += x; }
    __shared__ int wsum[4];
    if (lane == 63) wsum[w] = incl;
    __syncthreads();
    int woff = 0;
    for (int i = 0; i < w; ++i) woff += wsum[i];
    int excl = incl - s + woff + part[b];
#pragma unroll
    for (int k = 0; k < 4; ++k) {
        int id = i0 + k;
        if (id < n) { off[id] = excl; cur[id] = excl; }
        excl += v[k];
    }
    if (b == 0 && t == 0) off[n] = total;
}

// ---------------- partition base cursors from off[] ----------------
__global__ void pcur_init(const int* __restrict__ off_h, int n_ent, int shiftH,
                          int* __restrict__ pcurK,
                          const int* __restrict__ off_u, int n_usr, int shiftU,
                          int* __restrict__ pcurU) {
    int t = threadIdx.x;
    if (t < NPART) {
        pcurK[t] = off_h[min(t << shiftH, n_ent)];
        pcurU[t] = off_u[min(t << shiftU, n_usr)];
    }
}

// ---- P3: self-reserving dense bucket write  MERGED with hop-1 proj (both streaming) ----
__global__ void __launch_bounds__(256) p3proj_kernel(
        const int* __restrict__ head, const int* __restrict__ tail,
        const int* __restrict__ etype, int E, int shiftH,
        int* __restrict__ pcurK, uint2v* __restrict__ bktK,
        const int* __restrict__ iu, const int* __restrict__ ii,
        const float* __restrict__ w, int EI, int shiftU,
        int* __restrict__ pcurU, uint2v* __restrict__ bktU,
        const float* __restrict__ e_in, const float* __restrict__ W,
        unsigned* __restrict__ packed, int n_ent) {
    __shared__ float sh[64 * 64];
    int b = blockIdx.x;
    if (b >= NBK + NBU) {
        // ---- proj role: grid-stride over entity rows ----
        for (int i = threadIdx.x; i < 64 * 64; i += 256) sh[i] = W[i];
        __syncthreads();
        int lane = threadIdx.x & 63;
        int wid = (b - (NBK + NBU)) * 4 + (threadIdx.x >> 6);
        proj_rows(e_in, sh, packed, n_ent, wid, P3_PROJ * 4, lane);
        return;
    }
    int* lc = (int*)sh;
    if (threadIdx.x < NPART) lc[threadIdx.x] = 0;
    __syncthreads();
    if (b < NBK) {
        int chunk = (E + NBK - 1) / NBK;
        int lo = b * chunk, hi = min(lo + chunk, E);
        for (int e = lo + (int)threadIdx.x; e < hi; e += 256)
            atomicAdd(&lc[__builtin_nontemporal_load(&head[e]) >> shiftH], 1);
        __syncthreads();
        if (threadIdx.x < NPART)
            lc[threadIdx.x] = atomicAdd(&pcurK[threadIdx.x], lc[threadIdx.x]);
        __syncthreads();
        for (int e = lo + (int)threadIdx.x; e < hi; e += 256) {
            int h = __builtin_nontemporal_load(&head[e]);
            int tl = __builtin_nontemporal_load(&tail[e]);
            int ty = __builtin_nontemporal_load(&etype[e]);
            int pos = atomicAdd(&lc[h >> shiftH], 1);
            uint2v r; r.x = (unsigned)(tl | ((ty - 1) << 17)); r.y = (unsigned)h;
            __builtin_nontemporal_store(r, &bktK[pos]);
        }
    } else {
        int bb = b - NBK;
        int chunk = (EI + NBU - 1) / NBU;
        int lo = bb * chunk, hi = min(lo + chunk, EI);
        for (int e = lo + (int)threadIdx.x; e < hi; e += 256)
            atomicAdd(&lc[__builtin_nontemporal_load(&iu[e]) >> shiftU], 1);
        __syncthreads();
        if (threadIdx.x < NPART)
            lc[threadIdx.x] = atomicAdd(&pcurU[threadIdx.x], lc[threadIdx.x]);
        __syncthreads();
        for (int e = lo + (int)threadIdx.x; e < hi; e += 256) {
            int u = __builtin_nontemporal_load(&iu[e]);
            int it = __builtin_nontemporal_load(&ii[e]);
            float wv = __builtin_nontemporal_load(&w[e]);
            int pos = atomicAdd(&lc[u >> shiftU], 1);
            unsigned wq = (unsigned)(wv * 32767.f + 0.5f);
            uint2v r; r.x = (unsigned)it | (wq << 17); r.y = (unsigned)u;
            __builtin_nontemporal_store(r, &bktU[pos]);
        }
    }
}

// ---------------- P4: pure partition-local scatter into CSR col ----------------
__global__ void __launch_bounds__(256) p4_fill_kernel(
        const uint2v* __restrict__ bktK, const int* __restrict__ off_h, int n_ent, int shiftH,
        int* __restrict__ cur_h, int* __restrict__ col_h,
        const uint2v* __restrict__ bktU, const int* __restrict__ off_u, int n_usr, int shiftU,
        int* __restrict__ cur_u, unsigned* __restrict__ col_ui) {
    int b = blockIdx.x;
    if (b < P4_KG) {
        int p = b & (NPART - 1), s = b >> 5;            // 32 slices per partition
        int st = off_h[min(p << shiftH, n_ent)];
        int en = off_h[min((p + 1) << shiftH, n_ent)];
        long long len = en - st;
        int lo = st + (int)(len * s / 32);
        int hi = st + (int)(len * (s + 1) / 32);
        for (int i = lo + (int)threadIdx.x; i < hi; i += 256) {
            uint2v r = __builtin_nontemporal_load(&bktK[i]);
            int pos = atomicAdd(&cur_h[r.y], 1);
            col_h[pos] = (int)r.x;
        }
    } else {
        int bb = b - P4_KG;
        int p = bb & (NPART - 1), s = bb >> 5;          // 16 slices per partition
        int st = off_u[min(p << shiftU, n_usr)];
        int en = off_u[min((p + 1) << shiftU, n_usr)];
        long long len = en - st;
        int lo = st + (int)(len * s / 16);
        int hi = st + (int)(len * (s + 1) / 16);
        for (int i = lo + (int)threadIdx.x; i < hi; i += 256) {
            uint2v r = __builtin_nontemporal_load(&bktU[i]);
            int pos = atomicAdd(&cur_u[r.y], 1);
            col_ui[pos] = r.x;
        }
    }
}

// ------- fused agg: KG = 2 dims/lane, 2 edges/wave;  UI = per-user weighted agg -------
// HOP1 epilogue emits the normalized row as bf16 (enorm) for the cheap proj2b pass.
#define KG_PAIR(J, P, W) {                                                  \
        int rr = (P) >> 17;                                                 \
        float rl0 = relS[rr * EMB + dd], rl1 = relS[rr * EMB + dd + 1];     \
        float pt0 = bfhi(W.x), pt1 = bfhi(W.y);                             \
        float et0 = bflo(W.x), et1 = bflo(W.y);                             \
        float prod = fmaf(q0 * rl0, pt0, q1 * rl1 * pt1);                   \
        prod += __shfl_xor(prod, 1, 64);                                    \
        prod += __shfl_xor(prod, 2, 64);                                    \
        prod += __shfl_xor(prod, 4, 64);                                    \
        prod += __shfl_xor(prod, 8, 64);                                    \
        float ex = __expf(prod * INV_SQRT_DK);                              \
        if ((J) + half >= e) ex = 0.f;                                      \
        den += ex;                                                          \
        num0 = fmaf(ex * rl0, et0, num0);                                   \
        num1 = fmaf(ex * rl1, et1, num1); }

template <bool HOP1>
__global__ void __launch_bounds__(256) agg_fused_kernel(
        const unsigned* __restrict__ pk,          // gather table for this hop
        unsigned short* __restrict__ enorm_out,   // HOP1: bf16 normalized rows
        const float* __restrict__ rel_emb,
        const int* __restrict__ off_h, const int* __restrict__ col_h,
        const int* __restrict__ off_u, const unsigned* __restrict__ col_ui,
        const float* __restrict__ e_base, float* __restrict__ e_res, int n_ent,
        const float* __restrict__ u_base, float* __restrict__ u_res,
        int n_usr, int kgBlocks, int totalBlocks) {
    __shared__ float relS[16 * EMB];
    int bid = blockIdx.x;
    // Bresenham interleave of kg-role and ui-role blocks
    size_t lo = (size_t)bid * kgBlocks / totalBlocks;
    size_t hi = (size_t)(bid + 1) * kgBlocks / totalBlocks;
    int lane = threadIdx.x & 63;
    int wslot = threadIdx.x >> 6;

    if (hi > lo) {
        // ---------------- KG entity block: 2 dims/lane, 2 edges/wave ----------------
        for (int i = threadIdx.x; i < 16 * EMB; i += blockDim.x) relS[i] = rel_emb[i];
        __syncthreads();
        int wid = (int)lo * 4 + wslot;
        if (wid >= n_ent) return;
        int s = off_h[wid], e = off_h[wid + 1];
        int half = lane >> 5;
        int sub  = lane & 31;
        int dd   = sub * 2;
        uint2 qw = *(const uint2*)&pk[(size_t)wid * EMB + dd];
        float q0 = bfhi(qw.x), q1 = bfhi(qw.y);
        float num0 = 0.f, num1 = 0.f, den = 0.f;
        int j = s;
        for (; j + 3 < e; j += 4) {           // 2 pairs (4 edges), no dummies possible
            int pA = col_h[j + half];
            int pB = col_h[j + 2 + half];
            uint2 wA = *(const uint2*)&pk[(size_t)(pA & 131071) * EMB + dd];
            uint2 wB = *(const uint2*)&pk[(size_t)(pB & 131071) * EMB + dd];
            KG_PAIR(j, pA, wA);
            KG_PAIR(j + 2, pB, wB);
        }
        for (; j < e; j += 2) {               // remainder pair, may have a dummy lane-half
            int jj = j + half; if (jj >= e) jj = e - 1;
            int pA = col_h[jj];
            uint2 wA = *(const uint2*)&pk[(size_t)(pA & 131071) * EMB + dd];
            KG_PAIR(j, pA, wA);
        }
        // combine the two edge-halves (once per node); both halves end identical
        den  += __shfl_xor(den, 32, 64);
        num0 += __shfl_xor(num0, 32, 64);
        num1 += __shfl_xor(num1, 32, 64);
        float inv = (e > s) ? 1.f / den : 0.f;   // deferred softmax division
        float v0 = num0 * inv, v1 = num1 * inv;
        float ss = fmaf(v0, v0, v1 * v1);
#pragma unroll
        for (int m = 1; m <= 16; m <<= 1) ss += __shfl_xor(ss, m, 64);
        float rn = 1.f / fmaxf(sqrtf(ss), 1e-12f);
        float o0 = v0 * rn, o1 = v1 * rn;       // dims (2*sub, 2*sub+1), all 64 lanes
        // element belonging to THIS lane (dim = lane)
        float a0 = __shfl(o0, lane >> 1, 64);
        float a1 = __shfl(o1, lane >> 1, 64);
        float em = (lane & 1) ? a1 : a0;
        size_t ix = (size_t)wid * EMB + lane;
        if (HOP1) {
            enorm_out[ix] = f2bf(em);
            e_res[ix] = e_base[ix] + em;
        } else {
            e_res[ix] += em;
        }
    } else {
        // ---------------- UI user block (values from bflo(pk)) ----------------
        int wid = (bid - (int)lo) * 4 + wslot;
        if (wid >= n_usr) return;
        int s = off_u[wid], e = off_u[wid + 1];
        float acc = 0.f;
        int j = s;
        for (; j + 3 < e; j += 4) {
            unsigned c0 = col_ui[j],     c1 = col_ui[j + 1];
            unsigned c2 = col_ui[j + 2], c3 = col_ui[j + 3];
            float w0 = (c0 >> 17) * (1.f / 32767.f);
            float w1 = (c1 >> 17) * (1.f / 32767.f);
            float w2 = (c2 >> 17) * (1.f / 32767.f);
            float w3 = (c3 >> 17) * (1.f / 32767.f);
            float v0 = bflo(pk[(size_t)(c0 & 131071u) * EMB + lane]);
            float v1 = bflo(pk[(size_t)(c1 & 131071u) * EMB + lane]);
            float v2 = bflo(pk[(size_t)(c2 & 131071u) * EMB + lane]);
            float v3 = bflo(pk[(size_t)(c3 & 131071u) * EMB + lane]);
            acc = fmaf(w0, v0, acc);
            acc = fmaf(w1, v1, acc);
            acc = fmaf(w2, v2, acc);
            acc = fmaf(w3, v3, acc);
        }
        for (; j < e; ++j) {
            unsigned c = col_ui[j];
            acc = fmaf((c >> 17) * (1.f / 32767.f),
                       bflo(pk[(size_t)(c & 131071u) * EMB + lane]), acc);
        }
        float ss = acc * acc;
#pragma unroll
        for (int m = 1; m <= 32; m <<= 1) ss += __shfl_xor(ss, m, 64);
        float o = acc / fmaxf(sqrtf(ss), 1e-12f);
        size_t ix = (size_t)wid * EMB + lane;
        if (HOP1) u_res[ix] = u_base[ix] + o;
        else      u_res[ix] += o;
    }
}

extern "C" void kernel_launch(void* const* d_in, const int* in_sizes, int n_in,
                              void* d_out, int out_size, void* d_ws, size_t ws_size,
                              hipStream_t stream) {
    const float* user_emb   = (const float*)d_in[0];
    const float* entity_emb = (const float*)d_in[1];
    const int*   edge_index = (const int*)d_in[2];   // [2, E]
    const int*   edge_type  = (const int*)d_in[3];   // [E]
    const int*   inter_edge = (const int*)d_in[4];   // [2, EI]
    const float* inter_w    = (const float*)d_in[5]; // [EI]
    const float* W_Q        = (const float*)d_in[6]; // [64,64]
    const float* rel_emb    = (const float*)d_in[7]; // [16,64]

    const int E     = in_sizes[3];
    const int EI    = in_sizes[5];
    const int n_ent = in_sizes[1] / EMB;
    const int n_usr = in_sizes[0] / EMB;

    const int* head = edge_index;
    const int* tail = edge_index + E;
    const int* iu   = inter_edge;
    const int* ii   = inter_edge + EI;

    // partition shifts: smallest shift with <= NPART partitions
    int shiftH = 0; while (((n_ent + (1 << shiftH) - 1) >> shiftH) > NPART) ++shiftH;
    int shiftU = 0; while (((n_usr + (1 << shiftU) - 1) >> shiftU) > NPART) ++shiftU;

    // ---- workspace layout ----
    char* ws = (char*)d_ws;
    unsigned* packed  = (unsigned*)ws;         ws += (size_t)n_ent * EMB * 4;   // hop-1 table
    unsigned* packed2 = (unsigned*)ws;         ws += (size_t)n_ent * EMB * 4;   // hop-2 table
    unsigned short* enorm = (unsigned short*)ws; ws += (size_t)n_ent * EMB * 2; // agg1 -> proj2b
    int*      col_h  = (int*)ws;               ws += (size_t)E * 4;
    unsigned* col_ui = (unsigned*)ws;          ws += (size_t)EI * 4;
    int*   off_h = (int*)ws;                   ws += (size_t)(n_ent + 1) * 4;
    int*   off_u = (int*)ws;                   ws += (size_t)(n_usr + 1) * 4;
    int*   cur_h = (int*)ws;                   ws += (size_t)n_ent * 4;   // cur_h|cur_u adjacent
    int*   cur_u = (int*)ws;                   ws += (size_t)n_usr * 4;
    int*   partH = (int*)ws;                   ws += 256 * 4;
    int*   partU = (int*)ws;                   ws += 256 * 4;
    int*   pcurK = (int*)ws;                   ws += NPART * 4;
    int*   pcurU = (int*)ws;                   ws += NPART * 4;
    // buckets overlay packed2 (dead until agg1/proj2b write it; p4 consumes buckets first)
    uint2v* bktK = (uint2v*)packed2;           // E * 8 bytes
    uint2v* bktU = bktK + E;                   // EI * 8 bytes (24 MB <= 25.6 MB region)

    float* e_res = (float*)d_out;
    float* u_res = e_res + (size_t)n_ent * EMB;

    const int nbH = (n_ent + 1023) / 1024;     // 98  (<=256)
    const int nbU = (n_usr + 1023) / 1024;     // 49  (<=256)

    // ---- CSR build via partition counting-sort (reused by both hops) ----
    hipMemsetAsync(cur_h, 0, (size_t)(n_ent + n_usr) * 4, stream);
    p1_hist<<<(E + EI + 255) / 256, 256, 0, stream>>>(head, cur_h, E, iu, cur_u, EI);
    scan_partial_both<<<nbH + nbU, 256, 0, stream>>>(cur_h, partH, n_ent, nbH, cur_u, partU, n_usr);
    scan_block_both<<<1, 256, 0, stream>>>(partH, nbH, partU, nbU);
    scan_final_both<<<nbH + nbU, 256, 0, stream>>>(cur_h, partH, off_h, cur_h, n_ent, nbH, E,
                                                   cur_u, partU, off_u, cur_u, n_usr, EI);
    pcur_init<<<1, 64, 0, stream>>>(off_h, n_ent, shiftH, pcurK, off_u, n_usr, shiftU, pcurU);
    // bucket write merged with hop-1 proj (both streaming; no L2-resident set to disturb)
    p3proj_kernel<<<NBK + NBU + P3_PROJ, 256, 0, stream>>>(
        head, tail, edge_type, E, shiftH, pcurK, bktK,
        iu, ii, inter_w, EI, shiftU, pcurU, bktU,
        entity_emb, W_Q, packed, n_ent);
    // pure partition-local scatter (L2-resident col regions)
    p4_fill_kernel<<<P4_KG + P4_UI, 256, 0, stream>>>(
        bktK, off_h, n_ent, shiftH, cur_h, col_h,
        bktU, off_u, n_usr, shiftU, cur_u, col_ui);

    const int kgBlocks = (n_ent + 3) / 4;
    const int uiBlocks = (n_usr + 3) / 4;
    const int totalBlocks = kgBlocks + uiBlocks;

    // ---- hop 1 (table = packed; emits enorm for proj2b) ----
    agg_fused_kernel<true><<<totalBlocks, 256, 0, stream>>>(
        packed, enorm, rel_emb, off_h, col_h, off_u, col_ui,
        entity_emb, e_res, n_ent, user_emb, u_res, n_usr, kgBlocks, totalBlocks);

    // ---- hop-2 proj from bf16 norm rows ----
    proj2b_kernel<<<PROJ2_BLOCKS, 256, 0, stream>>>(enorm, W_Q, packed2, n_ent);

    // ---- hop 2 (table = packed2) ----
    agg_fused_kernel<false><<<totalBlocks, 256, 0, stream>>>(
        packed2, nullptr, rel_emb, off_h, col_h, off_u, col_ui,
        nullptr, e_res, n_ent, nullptr, u_res, n_usr, kgBlocks, totalBlocks);
}

// Round 12
// 715.064 us; speedup vs baseline: 1.0504x; 1.0386x over previous
//
#include <hip/hip_runtime.h>
#include <math.h>

#define EMB 64
static constexpr float INV_SQRT_DK = 0.17677669529663687f; // 1/sqrt(32)

#define NPARTK 64         // KG node-range partitions (4B bucket records: 11|4|17 bits)
#define NPARTU 32         // UI partitions (8B records)
#define NBK 512           // KG bucket blocks
#define NBU 192           // UI bucket blocks
#define P3_PROJ 1024      // proj-role blocks appended to p3 (streaming || streaming)
#define P4_KG 1024        // KG scatter blocks (16 slices x 64 partitions)
#define P4_UI 512         // UI scatter blocks (16 slices x 32 partitions)
#define PROJ2_BLOCKS 2048

typedef unsigned uint2v __attribute__((ext_vector_type(2)));

__device__ inline unsigned short f2bf(float f) {
    union { float f; unsigned u; } v; v.f = f;
    unsigned r = v.u + 0x7FFF + ((v.u >> 16) & 1);   // round-to-nearest-even
    return (unsigned short)(r >> 16);
}
__device__ inline float bfhi(unsigned w) {           // high 16 bits as bf16
    union { float f; unsigned u; } v; v.u = w & 0xFFFF0000u; return v.f;
}
__device__ inline float bflo(unsigned w) {           // low 16 bits as bf16
    union { float f; unsigned u; } v; v.u = w << 16; return v.f;
}
__device__ inline float bf2f(unsigned short b) {
    union { float f; unsigned u; } v; v.u = ((unsigned)b) << 16; return v.f;
}

// ---- hop-1 proj rows: packed=(bf16(e@W)<<16)|bf16(e); also e_bf=bf16(e) for UI ----
__device__ inline void proj_rows(const float* __restrict__ e, const float* __restrict__ Wl,
                                 unsigned* __restrict__ packed, unsigned short* __restrict__ e_bf,
                                 int n, int wid, int nw, int lane) {
    for (int r = wid; r < n; r += nw) {
        float x = e[(size_t)r * EMB + lane];
        float acc = 0.f;
#pragma unroll
        for (int k = 0; k < 64; ++k) {
            float ek = __shfl(x, k, 64);
            acc += ek * Wl[k * 64 + lane];
        }
        unsigned eb = f2bf(x);
        size_t ix = (size_t)r * EMB + lane;
        packed[ix] = (((unsigned)f2bf(acc)) << 16) | eb;
        e_bf[ix] = (unsigned short)eb;
    }
}

// ---- hop-2 proj from bf16 normalized rows ----
__global__ void __launch_bounds__(256) proj2b_kernel(
        const unsigned short* __restrict__ enorm, const float* __restrict__ W,
        unsigned* __restrict__ packed2, int n) {
    __shared__ float Wl[64 * 64];
    for (int i = threadIdx.x; i < 64 * 64; i += 256) Wl[i] = W[i];
    __syncthreads();
    int lane = threadIdx.x & 63;
    int wid = blockIdx.x * 4 + (threadIdx.x >> 6);
    int nw = PROJ2_BLOCKS * 4;
    for (int r = wid; r < n; r += nw) {
        unsigned short eb = enorm[(size_t)r * EMB + lane];
        float x = bf2f(eb);
        float acc = 0.f;
#pragma unroll
        for (int k = 0; k < 64; ++k) {
            float ek = __shfl(x, k, 64);
            acc += ek * Wl[k * 64 + lane];
        }
        packed2[(size_t)r * EMB + lane] = (((unsigned)f2bf(acc)) << 16) | eb;
    }
}

// ---------------- P1: per-node histogram only ----------------
__global__ void p1_hist(const int* __restrict__ head, int* __restrict__ cnt_h, int E,
                        const int* __restrict__ iu, int* __restrict__ cnt_u, int EI) {
    int i = blockIdx.x * blockDim.x + threadIdx.x;
    if (i < E) atomicAdd(&cnt_h[__builtin_nontemporal_load(&head[i])], 1);
    else if (i < E + EI) atomicAdd(&cnt_u[__builtin_nontemporal_load(&iu[i - E])], 1);
}

// ---------------- multi-block exclusive scan of node degrees (3 phases) ----------------
__global__ void scan_partial_both(const int* __restrict__ degH, int* __restrict__ partH,
                                  int nH, int nbH,
                                  const int* __restrict__ degU, int* __restrict__ partU, int nU) {
    bool isU = (int)blockIdx.x >= nbH;
    const int* deg = isU ? degU : degH;
    int* part = isU ? partU : partH;
    int n = isU ? nU : nH;
    int b = isU ? blockIdx.x - nbH : blockIdx.x;
    int t = threadIdx.x;             // 256 threads, 4 elems each
    int i0 = b * 1024 + t * 4;
    int s = 0;
#pragma unroll
    for (int k = 0; k < 4; ++k) { int id = i0 + k; if (id < n) s += deg[id]; }
#pragma unroll
    for (int m = 1; m <= 32; m <<= 1) s += __shfl_xor(s, m, 64);
    __shared__ int wsum[4];
    if ((t & 63) == 0) wsum[t >> 6] = s;
    __syncthreads();
    if (t == 0) part[b] = wsum[0] + wsum[1] + wsum[2] + wsum[3];
}

__global__ void scan_block_both(int* __restrict__ partH, int nbH,
                                int* __restrict__ partU, int nbU) {
    __shared__ int sh[256];
    int t = threadIdx.x;
    for (int pass = 0; pass < 2; ++pass) {
        int* part = pass ? partU : partH;
        int nb = pass ? nbU : nbH;
        int v = (t < nb) ? part[t] : 0;
        sh[t] = v;
        __syncthreads();
        for (int d = 1; d < 256; d <<= 1) {
            int x = (t >= d) ? sh[t - d] : 0;
            __syncthreads();
            sh[t] += x;
            __syncthreads();
        }
        if (t < nb) part[t] = sh[t] - v; // exclusive
        __syncthreads();
    }
}

// writes both off[] and cur[] (fill cursor)
__global__ void scan_final_both(const int* __restrict__ degH, const int* __restrict__ partH,
                                int* __restrict__ offH, int* __restrict__ curH,
                                int nH, int nbH, int totalH,
                                const int* __restrict__ degU, const int* __restrict__ partU,
                                int* __restrict__ offU, int* __restrict__ curU,
                                int nU, int totalU) {
    bool isU = (int)blockIdx.x >= nbH;
    const int* deg = isU ? degU : degH;
    const int* part = isU ? partU : partH;
    int* off = isU ? offU : offH;
    int* cur = isU ? curU : curH;
    int n = isU ? nU : nH;
    int total = isU ? totalU : totalH;
    int b = isU ? blockIdx.x - nbH : blockIdx.x;
    int t = threadIdx.x;
    int lane = t & 63, w = t >> 6;
    int i0 = b * 1024 + t * 4;
    int v[4]; int s = 0;
#pragma unroll
    for (int k = 0; k < 4; ++k) { int id = i0 + k; v[k] = (id < n) ? deg[id] : 0; s += v[k]; }
    int incl = s;
#pragma unroll
    for (int d = 1; d < 64; d <<= 1) { int x = __shfl_up(incl, d, 64); if (lane >= d) incl += x; }
    __shared__ int wsum[4];
    if (lane == 63) wsum[w] = incl;
    __syncthreads();
    int woff = 0;
    for (int i = 0; i < w; ++i) woff += wsum[i];
    int excl = incl - s + woff + part[b];
#pragma unroll
    for (int k = 0; k < 4; ++k) {
        int id = i0 + k;
        if (id < n) { off[id] = excl; cur[id] = excl; }
        excl += v[k];
    }
    if (b == 0 && t == 0) off[n] = total;
}

// ---- P3: self-reserving dense bucket write  MERGED with hop-1 proj (both streaming) ----
// KG records are 4B: node_local(11) | type(4) | tail(17). Reservation reads off_h
// directly (pdK/pdU are zero-initialized deltas) — no pcur_init dispatch.
__global__ void __launch_bounds__(256) p3proj_kernel(
        const int* __restrict__ head, const int* __restrict__ tail,
        const int* __restrict__ etype, int E, int shiftH,
        const int* __restrict__ off_h, int* __restrict__ pdK, unsigned* __restrict__ bktK,
        const int* __restrict__ iu, const int* __restrict__ ii,
        const float* __restrict__ w, int EI, int shiftU,
        const int* __restrict__ off_u, int* __restrict__ pdU, uint2v* __restrict__ bktU,
        const float* __restrict__ e_in, const float* __restrict__ W,
        unsigned* __restrict__ packed, unsigned short* __restrict__ e_bf,
        int n_ent, int n_usr) {
    __shared__ float sh[64 * 64];
    int b = blockIdx.x;
    if (b >= NBK + NBU) {
        // ---- proj role: grid-stride over entity rows ----
        for (int i = threadIdx.x; i < 64 * 64; i += 256) sh[i] = W[i];
        __syncthreads();
        int lane = threadIdx.x & 63;
        int wid = (b - (NBK + NBU)) * 4 + (threadIdx.x >> 6);
        proj_rows(e_in, sh, packed, e_bf, n_ent, wid, P3_PROJ * 4, lane);
        return;
    }
    int* lc = (int*)sh;
    if (b < NBK) {
        if (threadIdx.x < NPARTK) lc[threadIdx.x] = 0;
        __syncthreads();
        int chunk = (E + NBK - 1) / NBK;
        int lo = b * chunk, hi = min(lo + chunk, E);
        for (int e = lo + (int)threadIdx.x; e < hi; e += 256)
            atomicAdd(&lc[__builtin_nontemporal_load(&head[e]) >> shiftH], 1);
        __syncthreads();
        if (threadIdx.x < NPARTK) {
            int base = off_h[min((int)threadIdx.x << shiftH, n_ent)];
            lc[threadIdx.x] = base + atomicAdd(&pdK[threadIdx.x], lc[threadIdx.x]);
        }
        __syncthreads();
        int mask = (1 << shiftH) - 1;
        for (int e = lo + (int)threadIdx.x; e < hi; e += 256) {
            int h = __builtin_nontemporal_load(&head[e]);
            int tl = __builtin_nontemporal_load(&tail[e]);
            int ty = __builtin_nontemporal_load(&etype[e]);
            int pos = atomicAdd(&lc[h >> shiftH], 1);
            unsigned r = ((unsigned)(h & mask) << 21) | (unsigned)(tl | ((ty - 1) << 17));
            __builtin_nontemporal_store(r, &bktK[pos]);
        }
    } else {
        int bb = b - NBK;
        if (threadIdx.x < NPARTU) lc[threadIdx.x] = 0;
        __syncthreads();
        int chunk = (EI + NBU - 1) / NBU;
        int lo = bb * chunk, hi = min(lo + chunk, EI);
        for (int e = lo + (int)threadIdx.x; e < hi; e += 256)
            atomicAdd(&lc[__builtin_nontemporal_load(&iu[e]) >> shiftU], 1);
        __syncthreads();
        if (threadIdx.x < NPARTU) {
            int base = off_u[min((int)threadIdx.x << shiftU, n_usr)];
            lc[threadIdx.x] = base + atomicAdd(&pdU[threadIdx.x], lc[threadIdx.x]);
        }
        __syncthreads();
        for (int e = lo + (int)threadIdx.x; e < hi; e += 256) {
            int u = __builtin_nontemporal_load(&iu[e]);
            int it = __builtin_nontemporal_load(&ii[e]);
            float wv = __builtin_nontemporal_load(&w[e]);
            int pos = atomicAdd(&lc[u >> shiftU], 1);
            unsigned wq = (unsigned)(wv * 32767.f + 0.5f);
            uint2v r; r.x = (unsigned)it | (wq << 17); r.y = (unsigned)u;
            __builtin_nontemporal_store(r, &bktU[pos]);
        }
    }
}

// ---------------- P4: pure partition-local scatter into CSR col ----------------
__global__ void __launch_bounds__(256) p4_fill_kernel(
        const unsigned* __restrict__ bktK, const int* __restrict__ off_h, int n_ent, int shiftH,
        int* __restrict__ cur_h, int* __restrict__ col_h,
        const uint2v* __restrict__ bktU, const int* __restrict__ off_u, int n_usr, int shiftU,
        int* __restrict__ cur_u, unsigned* __restrict__ col_ui) {
    int b = blockIdx.x;
    if (b < P4_KG) {
        int p = b & (NPARTK - 1), s = b >> 6;           // 16 slices per partition
        int st = off_h[min(p << shiftH, n_ent)];
        int en = off_h[min((p + 1) << shiftH, n_ent)];
        int plo = p << shiftH;
        long long len = en - st;
        int lo = st + (int)(len * s / 16);
        int hi = st + (int)(len * (s + 1) / 16);
        for (int i = lo + (int)threadIdx.x; i < hi; i += 256) {
            unsigned r = __builtin_nontemporal_load(&bktK[i]);
            int node = plo + (int)(r >> 21);
            int pos = atomicAdd(&cur_h[node], 1);
            col_h[pos] = (int)(r & 0x1FFFFFu);
        }
    } else {
        int bb = b - P4_KG;
        int p = bb & (NPARTU - 1), s = bb >> 5;         // 16 slices per partition
        int st = off_u[min(p << shiftU, n_usr)];
        int en = off_u[min((p + 1) << shiftU, n_usr)];
        long long len = en - st;
        int lo = st + (int)(len * s / 16);
        int hi = st + (int)(len * (s + 1) / 16);
        for (int i = lo + (int)threadIdx.x; i < hi; i += 256) {
            uint2v r = __builtin_nontemporal_load(&bktU[i]);
            int pos = atomicAdd(&cur_u[r.y], 1);
            col_ui[pos] = r.x;
        }
    }
}

// ------- fused agg, 4 dims/lane 4 edges/wave: KG attention + UI weighted agg -------
// lane = (slot<<4)|sub: slot = edge slot 0..3, sub = dim group (dims 4*sub..4*sub+3).
// Head0 = sub 0..7, head1 = sub 8..15; score reduce = 3-step xor over 8 lanes.
// Slot-combine at node end = xor16 + xor32.
template <bool HOP1>
__global__ void __launch_bounds__(256) agg_fused_kernel(
        const unsigned* __restrict__ pk,          // KG gather table for this hop
        const unsigned short* __restrict__ ebT,   // UI value table (hop1: e_bf, hop2: enorm)
        unsigned short* __restrict__ enorm_out,   // HOP1: bf16 normalized rows
        const float* __restrict__ rel_emb,
        const int* __restrict__ off_h, const int* __restrict__ col_h,
        const int* __restrict__ off_u, const unsigned* __restrict__ col_ui,
        const float* __restrict__ e_base, float* __restrict__ e_res, int n_ent,
        const float* __restrict__ u_base, float* __restrict__ u_res,
        int n_usr, int kgBlocks, int totalBlocks) {
    __shared__ float4 relS4[16 * 16];             // rel_emb as float4 rows
    int bid = blockIdx.x;
    // Bresenham interleave of kg-role and ui-role blocks
    size_t lo = (size_t)bid * kgBlocks / totalBlocks;
    size_t hi = (size_t)(bid + 1) * kgBlocks / totalBlocks;
    int lane = threadIdx.x & 63;
    int wslot = threadIdx.x >> 6;
    int slot = lane >> 4;
    int sub  = lane & 15;
    int dd   = sub * 4;

    if (hi > lo) {
        // ---------------- KG entity block ----------------
        for (int i = threadIdx.x; i < 16 * 16; i += blockDim.x)
            relS4[i] = ((const float4*)rel_emb)[i];
        __syncthreads();
        int wid = (int)lo * 4 + wslot;
        if (wid >= n_ent) return;
        int s = off_h[wid], e = off_h[wid + 1];
        uint4 qw = *(const uint4*)&pk[(size_t)wid * EMB + dd];
        float q0 = bfhi(qw.x), q1 = bfhi(qw.y), q2 = bfhi(qw.z), q3 = bfhi(qw.w);
        float num0 = 0.f, num1 = 0.f, num2 = 0.f, num3 = 0.f, den = 0.f;
        for (int j = s; j < e; j += 4) {
            int jj = j + slot;
            bool invd = jj >= e;
            if (invd) jj = e - 1;
            int p = col_h[jj];
            int tt = p & 131071;
            int rr = p >> 17;
            uint4 w = *(const uint4*)&pk[(size_t)tt * EMB + dd];
            float4 rl = relS4[rr * 16 + sub];
            float prod = q0 * rl.x * bfhi(w.x);
            prod = fmaf(q1 * rl.y, bfhi(w.y), prod);
            prod = fmaf(q2 * rl.z, bfhi(w.z), prod);
            prod = fmaf(q3 * rl.w, bfhi(w.w), prod);
            prod += __shfl_xor(prod, 1, 64);
            prod += __shfl_xor(prod, 2, 64);
            prod += __shfl_xor(prod, 4, 64);
            float ex = __expf(prod * INV_SQRT_DK);
            if (invd) ex = 0.f;
            den += ex;
            num0 = fmaf(ex * rl.x, bflo(w.x), num0);
            num1 = fmaf(ex * rl.y, bflo(w.y), num1);
            num2 = fmaf(ex * rl.z, bflo(w.z), num2);
            num3 = fmaf(ex * rl.w, bflo(w.w), num3);
        }
        // combine the 4 edge slots (once per node)
        den  += __shfl_xor(den, 16, 64);  den  += __shfl_xor(den, 32, 64);
        num0 += __shfl_xor(num0, 16, 64); num0 += __shfl_xor(num0, 32, 64);
        num1 += __shfl_xor(num1, 16, 64); num1 += __shfl_xor(num1, 32, 64);
        num2 += __shfl_xor(num2, 16, 64); num2 += __shfl_xor(num2, 32, 64);
        num3 += __shfl_xor(num3, 16, 64); num3 += __shfl_xor(num3, 32, 64);
        float dinv = (e > s) ? 1.f / den : 0.f;   // deferred softmax division
        float v0 = num0 * dinv, v1 = num1 * dinv, v2 = num2 * dinv, v3 = num3 * dinv;
        float ss = fmaf(v0, v0, fmaf(v1, v1, fmaf(v2, v2, v3 * v3)));
        ss += __shfl_xor(ss, 1, 64);
        ss += __shfl_xor(ss, 2, 64);
        ss += __shfl_xor(ss, 4, 64);
        ss += __shfl_xor(ss, 8, 64);
        float rn = 1.f / fmaxf(sqrtf(ss), 1e-12f);
        float o0 = v0 * rn, o1 = v1 * rn, o2 = v2 * rn, o3 = v3 * rn;
        if (slot == 0) {
            size_t ix = (size_t)wid * EMB + dd;
            if (HOP1) {
                ushort4 nb; nb.x = f2bf(o0); nb.y = f2bf(o1); nb.z = f2bf(o2); nb.w = f2bf(o3);
                *(ushort4*)&enorm_out[ix] = nb;
                float4 bv = *(const float4*)&e_base[ix];
                *(float4*)&e_res[ix] = make_float4(bv.x + o0, bv.y + o1, bv.z + o2, bv.w + o3);
            } else {
                float4 rv = *(const float4*)&e_res[ix];
                *(float4*)&e_res[ix] = make_float4(rv.x + o0, rv.y + o1, rv.z + o2, rv.w + o3);
            }
        }
    } else {
        // ---------------- UI user block (bf16 value table) ----------------
        int wid = (bid - (int)lo) * 4 + wslot;
        if (wid >= n_usr) return;
        int s = off_u[wid], e = off_u[wid + 1];
        float a0 = 0.f, a1 = 0.f, a2 = 0.f, a3 = 0.f;
        for (int j = s; j < e; j += 4) {
            int jj = j + slot;
            bool invd = jj >= e;
            if (invd) jj = e - 1;
            unsigned c = col_ui[jj];
            float wv = invd ? 0.f : (c >> 17) * (1.f / 32767.f);
            ushort4 v = *(const ushort4*)&ebT[(size_t)(c & 131071u) * EMB + dd];
            a0 = fmaf(wv, bf2f(v.x), a0);
            a1 = fmaf(wv, bf2f(v.y), a1);
            a2 = fmaf(wv, bf2f(v.z), a2);
            a3 = fmaf(wv, bf2f(v.w), a3);
        }
        a0 += __shfl_xor(a0, 16, 64); a0 += __shfl_xor(a0, 32, 64);
        a1 += __shfl_xor(a1, 16, 64); a1 += __shfl_xor(a1, 32, 64);
        a2 += __shfl_xor(a2, 16, 64); a2 += __shfl_xor(a2, 32, 64);
        a3 += __shfl_xor(a3, 16, 64); a3 += __shfl_xor(a3, 32, 64);
        float ss = fmaf(a0, a0, fmaf(a1, a1, fmaf(a2, a2, a3 * a3)));
        ss += __shfl_xor(ss, 1, 64);
        ss += __shfl_xor(ss, 2, 64);
        ss += __shfl_xor(ss, 4, 64);
        ss += __shfl_xor(ss, 8, 64);
        float rn = 1.f / fmaxf(sqrtf(ss), 1e-12f);
        float o0 = a0 * rn, o1 = a1 * rn, o2 = a2 * rn, o3 = a3 * rn;
        if (slot == 0) {
            size_t ix = (size_t)wid * EMB + dd;
            if (HOP1) {
                float4 bv = *(const float4*)&u_base[ix];
                *(float4*)&u_res[ix] = make_float4(bv.x + o0, bv.y + o1, bv.z + o2, bv.w + o3);
            } else {
                float4 rv = *(const float4*)&u_res[ix];
                *(float4*)&u_res[ix] = make_float4(rv.x + o0, rv.y + o1, rv.z + o2, rv.w + o3);
            }
        }
    }
}

extern "C" void kernel_launch(void* const* d_in, const int* in_sizes, int n_in,
                              void* d_out, int out_size, void* d_ws, size_t ws_size,
                              hipStream_t stream) {
    const float* user_emb   = (const float*)d_in[0];
    const float* entity_emb = (const float*)d_in[1];
    const int*   edge_index = (const int*)d_in[2];   // [2, E]
    const int*   edge_type  = (const int*)d_in[3];   // [E]
    const int*   inter_edge = (const int*)d_in[4];   // [2, EI]
    const float* inter_w    = (const float*)d_in[5]; // [EI]
    const float* W_Q        = (const float*)d_in[6]; // [64,64]
    const float* rel_emb    = (const float*)d_in[7]; // [16,64]

    const int E     = in_sizes[3];
    const int EI    = in_sizes[5];
    const int n_ent = in_sizes[1] / EMB;
    const int n_usr = in_sizes[0] / EMB;

    const int* head = edge_index;
    const int* tail = edge_index + E;
    const int* iu   = inter_edge;
    const int* ii   = inter_edge + EI;

    // partition shifts: smallest shift with <= NPART* partitions
    int shiftH = 0; while (((n_ent + (1 << shiftH) - 1) >> shiftH) > NPARTK) ++shiftH; // 11
    int shiftU = 0; while (((n_usr + (1 << shiftU) - 1) >> shiftU) > NPARTU) ++shiftU; // 11

    // ---- workspace layout ----
    char* ws = (char*)d_ws;
    unsigned* packed  = (unsigned*)ws;         ws += (size_t)n_ent * EMB * 4;   // hop-1 table
    unsigned* packed2 = (unsigned*)ws;         ws += (size_t)n_ent * EMB * 4;   // hop-2 table
    unsigned short* enorm = (unsigned short*)ws; ws += (size_t)n_ent * EMB * 2; // agg1 out / hop2 UI
    unsigned short* e_bf  = (unsigned short*)ws; ws += (size_t)n_ent * EMB * 2; // hop1 UI values
    int*      col_h  = (int*)ws;               ws += (size_t)E * 4;
    unsigned* col_ui = (unsigned*)ws;          ws += (size_t)EI * 4;
    int*   off_h = (int*)ws;                   ws += (size_t)(n_ent + 1) * 4;
    int*   off_u = (int*)ws;                   ws += (size_t)(n_usr + 1) * 4;
    int*   cur_h = (int*)ws;                   ws += (size_t)n_ent * 4;   // memset range start
    int*   cur_u = (int*)ws;                   ws += (size_t)n_usr * 4;
    int*   pdK   = (int*)ws;                   ws += NPARTK * 4;          // zeroed deltas
    int*   pdU   = (int*)ws;                   ws += NPARTU * 4;
    int*   partH = (int*)ws;                   ws += 256 * 4;
    int*   partU = (int*)ws;                   ws += 256 * 4;
    // buckets overlay packed2 (dead until proj2b writes it; p4 consumes buckets first)
    unsigned* bktK = (unsigned*)packed2;       // E * 4 bytes
    uint2v*   bktU = (uint2v*)(bktK + E);      // EI * 8 bytes (16 MB <= 25.6 MB region)

    float* e_res = (float*)d_out;
    float* u_res = e_res + (size_t)n_ent * EMB;

    const int nbH = (n_ent + 1023) / 1024;     // 98  (<=256)
    const int nbU = (n_usr + 1023) / 1024;     // 49  (<=256)

    // ---- CSR build via partition counting-sort (reused by both hops) ----
    hipMemsetAsync(cur_h, 0, ((size_t)(n_ent + n_usr) + NPARTK + NPARTU) * 4, stream);
    p1_hist<<<(E + EI + 255) / 256, 256, 0, stream>>>(head, cur_h, E, iu, cur_u, EI);
    scan_partial_both<<<nbH + nbU, 256, 0, stream>>>(cur_h, partH, n_ent, nbH, cur_u, partU, n_usr);
    scan_block_both<<<1, 256, 0, stream>>>(partH, nbH, partU, nbU);
    scan_final_both<<<nbH + nbU, 256, 0, stream>>>(cur_h, partH, off_h, cur_h, n_ent, nbH, E,
                                                   cur_u, partU, off_u, cur_u, n_usr, EI);
    // bucket write merged with hop-1 proj (both streaming)
    p3proj_kernel<<<NBK + NBU + P3_PROJ, 256, 0, stream>>>(
        head, tail, edge_type, E, shiftH, off_h, pdK, bktK,
        iu, ii, inter_w, EI, shiftU, off_u, pdU, bktU,
        entity_emb, W_Q, packed, e_bf, n_ent, n_usr);
    // pure partition-local scatter (L2-resident col regions)
    p4_fill_kernel<<<P4_KG + P4_UI, 256, 0, stream>>>(
        bktK, off_h, n_ent, shiftH, cur_h, col_h,
        bktU, off_u, n_usr, shiftU, cur_u, col_ui);

    const int kgBlocks = (n_ent + 3) / 4;
    const int uiBlocks = (n_usr + 3) / 4;
    const int totalBlocks = kgBlocks + uiBlocks;

    // ---- hop 1 (KG table = packed, UI table = e_bf; emits enorm) ----
    agg_fused_kernel<true><<<totalBlocks, 256, 0, stream>>>(
        packed, e_bf, enorm, rel_emb, off_h, col_h, off_u, col_ui,
        entity_emb, e_res, n_ent, user_emb, u_res, n_usr, kgBlocks, totalBlocks);

    // ---- hop-2 proj from bf16 norm rows ----
    proj2b_kernel<<<PROJ2_BLOCKS, 256, 0, stream>>>(enorm, W_Q, packed2, n_ent);

    // ---- hop 2 (KG table = packed2, UI table = enorm) ----
    agg_fused_kernel<false><<<totalBlocks, 256, 0, stream>>>(
        packed2, enorm, nullptr, rel_emb, off_h, col_h, off_u, col_ui,
        nullptr, e_res, n_ent, nullptr, u_res, n_usr, kgBlocks, totalBlocks);
}

// Round 13
// 537.998 us; speedup vs baseline: 1.3961x; 1.3291x over previous
//
#include <hip/hip_runtime.h>
#include <math.h>

#define EMB 64
static constexpr float INV_SQRT_DK = 0.17677669529663687f; // 1/sqrt(32)

#define NBK 256           // KG bucket blocks
#define NBU 96            // UI bucket blocks
#define P3_PROJ 1024      // proj-role blocks in K1 (streaming || streaming)
#define PROJ2_BLOCKS 2048
#define PSHIFT 9          // 512-node partitions
#define PRANGE 512
#define CAPK 14336        // per-partition bucket capacity (mean ~10.2k + 40 sigma)
#define CAPU 14336

typedef unsigned uint2v __attribute__((ext_vector_type(2)));

__device__ inline unsigned short f2bf(float f) {
    union { float f; unsigned u; } v; v.f = f;
    unsigned r = v.u + 0x7FFF + ((v.u >> 16) & 1);   // round-to-nearest-even
    return (unsigned short)(r >> 16);
}
__device__ inline float bfhi(unsigned w) {           // high 16 bits as bf16
    union { float f; unsigned u; } v; v.u = w & 0xFFFF0000u; return v.f;
}
__device__ inline float bflo(unsigned w) {           // low 16 bits as bf16
    union { float f; unsigned u; } v; v.u = w << 16; return v.f;
}
__device__ inline float bf2f(unsigned short b) {
    union { float f; unsigned u; } v; v.u = ((unsigned)b) << 16; return v.f;
}

// ---- hop-1 proj rows: packed=(bf16(e@W)<<16)|bf16(e); also e_bf=bf16(e) for UI ----
__device__ inline void proj_rows(const float* __restrict__ e, const float* __restrict__ Wl,
                                 unsigned* __restrict__ packed, unsigned short* __restrict__ e_bf,
                                 int n, int wid, int nw, int lane) {
    for (int r = wid; r < n; r += nw) {
        float x = e[(size_t)r * EMB + lane];
        float acc = 0.f;
#pragma unroll
        for (int k = 0; k < 64; ++k) {
            float ek = __shfl(x, k, 64);
            acc += ek * Wl[k * 64 + lane];
        }
        unsigned eb = f2bf(x);
        size_t ix = (size_t)r * EMB + lane;
        packed[ix] = (((unsigned)f2bf(acc)) << 16) | eb;
        e_bf[ix] = (unsigned short)eb;
    }
}

// ---- hop-2 proj from bf16 normalized rows ----
__global__ void __launch_bounds__(256) proj2b_kernel(
        const unsigned short* __restrict__ enorm, const float* __restrict__ W,
        unsigned* __restrict__ packed2, int n) {
    __shared__ float Wl[64 * 64];
    for (int i = threadIdx.x; i < 64 * 64; i += 256) Wl[i] = W[i];
    __syncthreads();
    int lane = threadIdx.x & 63;
    int wid = blockIdx.x * 4 + (threadIdx.x >> 6);
    int nw = PROJ2_BLOCKS * 4;
    for (int r = wid; r < n; r += nw) {
        unsigned short eb = enorm[(size_t)r * EMB + lane];
        float x = bf2f(eb);
        float acc = 0.f;
#pragma unroll
        for (int k = 0; k < 64; ++k) {
            float ek = __shfl(x, k, 64);
            acc += ek * Wl[k * 64 + lane];
        }
        packed2[(size_t)r * EMB + lane] = (((unsigned)f2bf(acc)) << 16) | eb;
    }
}

// ---- K1: fixed-capacity partition bucketing (KG 4B recs, UI 8B recs) MERGED with proj ----
// KG record: local(9) << 21 | type(4) << 17 | tail(17). Partition base = p*CAP (no scan).
__global__ void __launch_bounds__(256) k1_bucket_proj(
        const int* __restrict__ head, const int* __restrict__ tail,
        const int* __restrict__ etype, int E,
        int* __restrict__ pdK, unsigned* __restrict__ bktK,
        const int* __restrict__ iu, const int* __restrict__ ii,
        const float* __restrict__ w, int EI,
        int* __restrict__ pdU, uint2v* __restrict__ bktU,
        const float* __restrict__ e_in, const float* __restrict__ W,
        unsigned* __restrict__ packed, unsigned short* __restrict__ e_bf,
        int n_ent, int nPartH, int nPartU) {
    __shared__ float sh[64 * 64];
    int b = blockIdx.x;
    if (b >= NBK + NBU) {
        // ---- proj role: grid-stride over entity rows ----
        for (int i = threadIdx.x; i < 64 * 64; i += 256) sh[i] = W[i];
        __syncthreads();
        int lane = threadIdx.x & 63;
        int wid = (b - (NBK + NBU)) * 4 + (threadIdx.x >> 6);
        proj_rows(e_in, sh, packed, e_bf, n_ent, wid, P3_PROJ * 4, lane);
        return;
    }
    int* lc = (int*)sh;
    lc[threadIdx.x] = 0;
    __syncthreads();
    if (b < NBK) {
        int chunk = (E + NBK - 1) / NBK;
        int lo = b * chunk, hi = min(lo + chunk, E);
        for (int e = lo + (int)threadIdx.x; e < hi; e += 256)
            atomicAdd(&lc[__builtin_nontemporal_load(&head[e]) >> PSHIFT], 1);
        __syncthreads();
        if ((int)threadIdx.x < nPartH)
            lc[threadIdx.x] = threadIdx.x * CAPK + atomicAdd(&pdK[threadIdx.x], lc[threadIdx.x]);
        __syncthreads();
        for (int e = lo + (int)threadIdx.x; e < hi; e += 256) {
            int h = __builtin_nontemporal_load(&head[e]);
            int tl = __builtin_nontemporal_load(&tail[e]);
            int ty = __builtin_nontemporal_load(&etype[e]);
            int pos = atomicAdd(&lc[h >> PSHIFT], 1);
            unsigned r = ((unsigned)(h & (PRANGE - 1)) << 21) | (unsigned)(tl | ((ty - 1) << 17));
            __builtin_nontemporal_store(r, &bktK[pos]);
        }
    } else {
        int bb = b - NBK;
        int chunk = (EI + NBU - 1) / NBU;
        int lo = bb * chunk, hi = min(lo + chunk, EI);
        for (int e = lo + (int)threadIdx.x; e < hi; e += 256)
            atomicAdd(&lc[__builtin_nontemporal_load(&iu[e]) >> PSHIFT], 1);
        __syncthreads();
        if ((int)threadIdx.x < nPartU)
            lc[threadIdx.x] = threadIdx.x * CAPU + atomicAdd(&pdU[threadIdx.x], lc[threadIdx.x]);
        __syncthreads();
        for (int e = lo + (int)threadIdx.x; e < hi; e += 256) {
            int u = __builtin_nontemporal_load(&iu[e]);
            int it = __builtin_nontemporal_load(&ii[e]);
            float wv = __builtin_nontemporal_load(&w[e]);
            int pos = atomicAdd(&lc[u >> PSHIFT], 1);
            unsigned wq = (unsigned)(wv * 32767.f + 0.5f);
            uint2v r; r.x = (unsigned)it | (wq << 17); r.y = (unsigned)u;
            __builtin_nontemporal_store(r, &bktU[pos]);
        }
    }
}

// ---- K2: per-partition LDS counting sort -> node-sorted col[] + off[] (no global atomics) ----
__global__ void __launch_bounds__(256) k2_sort(
        const unsigned* __restrict__ bktK, const int* __restrict__ pdK,
        int* __restrict__ off_h, int* __restrict__ col_h, int n_ent, int nPartH, int E,
        const uint2v* __restrict__ bktU, const int* __restrict__ pdU,
        int* __restrict__ off_u, unsigned* __restrict__ col_ui, int n_usr, int nPartU, int EI) {
    __shared__ int hist[PRANGE];
    __shared__ int wsum[4];
    int t = threadIdx.x;
    int lane = t & 63, wv = t >> 6;
    int b = blockIdx.x;
    bool isU = b >= nPartH;
    int p = isU ? b - nPartH : b;
    const int* pd = isU ? pdU : pdK;
    int cnt = min(pd[p], isU ? CAPU : CAPK);
    // S_p = sum of partition counts before p (pd entries beyond nPart are zero)
    int contrib = (t < p) ? pd[t] : 0;
#pragma unroll
    for (int m = 1; m <= 32; m <<= 1) contrib += __shfl_xor(contrib, m, 64);
    if (lane == 0) wsum[wv] = contrib;
    hist[t] = 0; hist[t + 256] = 0;
    __syncthreads();
    int Sp = wsum[0] + wsum[1] + wsum[2] + wsum[3];
    // pass 1: histogram of node-locals
    if (!isU) {
        const unsigned* bk = bktK + (size_t)p * CAPK;
        for (int i = t; i < cnt; i += 256)
            atomicAdd(&hist[__builtin_nontemporal_load(&bk[i]) >> 21], 1);
    } else {
        const uint2v* bu = bktU + (size_t)p * CAPU;
        int plo = p << PSHIFT;
        for (int i = t; i < cnt; i += 256) {
            uint2v r = __builtin_nontemporal_load(&bu[i]);
            atomicAdd(&hist[(int)r.y - plo], 1);
        }
    }
    __syncthreads();
    // exclusive scan of 512 bins (pairs per thread)
    int v0 = hist[2 * t], v1 = hist[2 * t + 1];
    int ps = v0 + v1;
    int incl = ps;
#pragma unroll
    for (int d = 1; d <= 32; d <<= 1) { int x = __shfl_up(incl, d, 64); if (lane >= d) incl += x; }
    __syncthreads();                   // hist reads done before overwrite below
    if (lane == 63) wsum[wv] = incl;
    __syncthreads();
    int woff = 0;
    for (int i = 0; i < wv; ++i) woff += wsum[i];
    int ex = incl - ps + woff;         // exclusive over pairs
    int plo = p << PSHIFT;
    int nmax = isU ? n_usr : n_ent;
    int* off = isU ? off_u : off_h;
    if (plo + 2 * t < nmax)     off[plo + 2 * t]     = Sp + ex;
    if (plo + 2 * t + 1 < nmax) off[plo + 2 * t + 1] = Sp + ex + v0;
    hist[2 * t] = Sp + ex;             // reuse hist as write cursors
    hist[2 * t + 1] = Sp + ex + v0;
    if (b == 0 && t == 0) off_h[n_ent] = E;
    if (b == nPartH && t == 0) off_u[n_usr] = EI;
    __syncthreads();
    // pass 2: scatter into node-sorted col
    if (!isU) {
        const unsigned* bk = bktK + (size_t)p * CAPK;
        for (int i = t; i < cnt; i += 256) {
            unsigned r = __builtin_nontemporal_load(&bk[i]);
            int pos = atomicAdd(&hist[r >> 21], 1);
            col_h[pos] = (int)(r & 0x1FFFFFu);
        }
    } else {
        const uint2v* bu = bktU + (size_t)p * CAPU;
        for (int i = t; i < cnt; i += 256) {
            uint2v r = __builtin_nontemporal_load(&bu[i]);
            int pos = atomicAdd(&hist[(int)r.y - plo], 1);
            col_ui[pos] = r.x;
        }
    }
}

// ------- fused agg, 4 dims/lane 4 edges/wave: KG attention + UI weighted agg -------
template <bool HOP1>
__global__ void __launch_bounds__(256) agg_fused_kernel(
        const unsigned* __restrict__ pk,          // KG gather table for this hop
        const unsigned short* __restrict__ ebT,   // UI value table (hop1: e_bf, hop2: enorm)
        unsigned short* __restrict__ enorm_out,   // HOP1: bf16 normalized rows
        const float* __restrict__ rel_emb,
        const int* __restrict__ off_h, const int* __restrict__ col_h,
        const int* __restrict__ off_u, const unsigned* __restrict__ col_ui,
        const float* __restrict__ e_base, float* __restrict__ e_res, int n_ent,
        const float* __restrict__ u_base, float* __restrict__ u_res,
        int n_usr, int kgBlocks, int totalBlocks) {
    __shared__ float4 relS4[16 * 16];             // rel_emb as float4 rows
    int bid = blockIdx.x;
    // Bresenham interleave of kg-role and ui-role blocks
    size_t lo = (size_t)bid * kgBlocks / totalBlocks;
    size_t hi = (size_t)(bid + 1) * kgBlocks / totalBlocks;
    int lane = threadIdx.x & 63;
    int wslot = threadIdx.x >> 6;
    int slot = lane >> 4;
    int sub  = lane & 15;
    int dd   = sub * 4;

    if (hi > lo) {
        // ---------------- KG entity block ----------------
        for (int i = threadIdx.x; i < 16 * 16; i += blockDim.x)
            relS4[i] = ((const float4*)rel_emb)[i];
        __syncthreads();
        int wid = (int)lo * 4 + wslot;
        if (wid >= n_ent) return;
        int s = off_h[wid], e = off_h[wid + 1];
        uint4 qw = *(const uint4*)&pk[(size_t)wid * EMB + dd];
        float q0 = bfhi(qw.x), q1 = bfhi(qw.y), q2 = bfhi(qw.z), q3 = bfhi(qw.w);
        float num0 = 0.f, num1 = 0.f, num2 = 0.f, num3 = 0.f, den = 0.f;
        for (int j = s; j < e; j += 4) {
            int jj = j + slot;
            bool invd = jj >= e;
            if (invd) jj = e - 1;
            int p = col_h[jj];
            int tt = p & 131071;
            int rr = p >> 17;
            uint4 w = *(const uint4*)&pk[(size_t)tt * EMB + dd];
            float4 rl = relS4[rr * 16 + sub];
            float prod = q0 * rl.x * bfhi(w.x);
            prod = fmaf(q1 * rl.y, bfhi(w.y), prod);
            prod = fmaf(q2 * rl.z, bfhi(w.z), prod);
            prod = fmaf(q3 * rl.w, bfhi(w.w), prod);
            prod += __shfl_xor(prod, 1, 64);
            prod += __shfl_xor(prod, 2, 64);
            prod += __shfl_xor(prod, 4, 64);
            float ex = __expf(prod * INV_SQRT_DK);
            if (invd) ex = 0.f;
            den += ex;
            num0 = fmaf(ex * rl.x, bflo(w.x), num0);
            num1 = fmaf(ex * rl.y, bflo(w.y), num1);
            num2 = fmaf(ex * rl.z, bflo(w.z), num2);
            num3 = fmaf(ex * rl.w, bflo(w.w), num3);
        }
        // combine the 4 edge slots (once per node)
        den  += __shfl_xor(den, 16, 64);  den  += __shfl_xor(den, 32, 64);
        num0 += __shfl_xor(num0, 16, 64); num0 += __shfl_xor(num0, 32, 64);
        num1 += __shfl_xor(num1, 16, 64); num1 += __shfl_xor(num1, 32, 64);
        num2 += __shfl_xor(num2, 16, 64); num2 += __shfl_xor(num2, 32, 64);
        num3 += __shfl_xor(num3, 16, 64); num3 += __shfl_xor(num3, 32, 64);
        float dinv = (e > s) ? 1.f / den : 0.f;   // deferred softmax division
        float v0 = num0 * dinv, v1 = num1 * dinv, v2 = num2 * dinv, v3 = num3 * dinv;
        float ss = fmaf(v0, v0, fmaf(v1, v1, fmaf(v2, v2, v3 * v3)));
        ss += __shfl_xor(ss, 1, 64);
        ss += __shfl_xor(ss, 2, 64);
        ss += __shfl_xor(ss, 4, 64);
        ss += __shfl_xor(ss, 8, 64);
        float rn = 1.f / fmaxf(sqrtf(ss), 1e-12f);
        float o0 = v0 * rn, o1 = v1 * rn, o2 = v2 * rn, o3 = v3 * rn;
        if (slot == 0) {
            size_t ix = (size_t)wid * EMB + dd;
            if (HOP1) {
                ushort4 nb; nb.x = f2bf(o0); nb.y = f2bf(o1); nb.z = f2bf(o2); nb.w = f2bf(o3);
                *(ushort4*)&enorm_out[ix] = nb;
                float4 bv = *(const float4*)&e_base[ix];
                *(float4*)&e_res[ix] = make_float4(bv.x + o0, bv.y + o1, bv.z + o2, bv.w + o3);
            } else {
                float4 rv = *(const float4*)&e_res[ix];
                *(float4*)&e_res[ix] = make_float4(rv.x + o0, rv.y + o1, rv.z + o2, rv.w + o3);
            }
        }
    } else {
        // ---------------- UI user block (bf16 value table) ----------------
        int wid = (bid - (int)lo) * 4 + wslot;
        if (wid >= n_usr) return;
        int s = off_u[wid], e = off_u[wid + 1];
        float a0 = 0.f, a1 = 0.f, a2 = 0.f, a3 = 0.f;
        for (int j = s; j < e; j += 4) {
            int jj = j + slot;
            bool invd = jj >= e;
            if (invd) jj = e - 1;
            unsigned c = col_ui[jj];
            float wv = invd ? 0.f : (c >> 17) * (1.f / 32767.f);
            ushort4 v = *(const ushort4*)&ebT[(size_t)(c & 131071u) * EMB + dd];
            a0 = fmaf(wv, bf2f(v.x), a0);
            a1 = fmaf(wv, bf2f(v.y), a1);
            a2 = fmaf(wv, bf2f(v.z), a2);
            a3 = fmaf(wv, bf2f(v.w), a3);
        }
        a0 += __shfl_xor(a0, 16, 64); a0 += __shfl_xor(a0, 32, 64);
        a1 += __shfl_xor(a1, 16, 64); a1 += __shfl_xor(a1, 32, 64);
        a2 += __shfl_xor(a2, 16, 64); a2 += __shfl_xor(a2, 32, 64);
        a3 += __shfl_xor(a3, 16, 64); a3 += __shfl_xor(a3, 32, 64);
        float ss = fmaf(a0, a0, fmaf(a1, a1, fmaf(a2, a2, a3 * a3)));
        ss += __shfl_xor(ss, 1, 64);
        ss += __shfl_xor(ss, 2, 64);
        ss += __shfl_xor(ss, 4, 64);
        ss += __shfl_xor(ss, 8, 64);
        float rn = 1.f / fmaxf(sqrtf(ss), 1e-12f);
        float o0 = a0 * rn, o1 = a1 * rn, o2 = a2 * rn, o3 = a3 * rn;
        if (slot == 0) {
            size_t ix = (size_t)wid * EMB + dd;
            if (HOP1) {
                float4 bv = *(const float4*)&u_base[ix];
                *(float4*)&u_res[ix] = make_float4(bv.x + o0, bv.y + o1, bv.z + o2, bv.w + o3);
            } else {
                float4 rv = *(const float4*)&u_res[ix];
                *(float4*)&u_res[ix] = make_float4(rv.x + o0, rv.y + o1, rv.z + o2, rv.w + o3);
            }
        }
    }
}

extern "C" void kernel_launch(void* const* d_in, const int* in_sizes, int n_in,
                              void* d_out, int out_size, void* d_ws, size_t ws_size,
                              hipStream_t stream) {
    const float* user_emb   = (const float*)d_in[0];
    const float* entity_emb = (const float*)d_in[1];
    const int*   edge_index = (const int*)d_in[2];   // [2, E]
    const int*   edge_type  = (const int*)d_in[3];   // [E]
    const int*   inter_edge = (const int*)d_in[4];   // [2, EI]
    const float* inter_w    = (const float*)d_in[5]; // [EI]
    const float* W_Q        = (const float*)d_in[6]; // [64,64]
    const float* rel_emb    = (const float*)d_in[7]; // [16,64]

    const int E     = in_sizes[3];
    const int EI    = in_sizes[5];
    const int n_ent = in_sizes[1] / EMB;
    const int n_usr = in_sizes[0] / EMB;

    const int* head = edge_index;
    const int* tail = edge_index + E;
    const int* iu   = inter_edge;
    const int* ii   = inter_edge + EI;

    const int nPartH = (n_ent + PRANGE - 1) >> PSHIFT;   // 196 (<=256)
    const int nPartU = (n_usr + PRANGE - 1) >> PSHIFT;   // 98  (<=256)

    // ---- workspace layout ----
    char* ws = (char*)d_ws;
    unsigned* packed  = (unsigned*)ws;         ws += (size_t)n_ent * EMB * 4;   // hop-1 table
    unsigned* packed2 = (unsigned*)ws;         ws += (size_t)n_ent * EMB * 4;   // hop-2 table
    unsigned short* enorm = (unsigned short*)ws; ws += (size_t)n_ent * EMB * 2; // agg1 out / hop2 UI
    unsigned short* e_bf  = (unsigned short*)ws; ws += (size_t)n_ent * EMB * 2; // hop1 UI values
    int*      col_h  = (int*)ws;               ws += (size_t)E * 4;
    unsigned* col_ui = (unsigned*)ws;          ws += (size_t)EI * 4;
    int*   off_h = (int*)ws;                   ws += (size_t)(n_ent + 1) * 4;
    int*   off_u = (int*)ws;                   ws += (size_t)(n_usr + 1) * 4;
    int*   pdK   = (int*)ws;                   ws += 256 * 4;   // zeroed partition counts
    int*   pdU   = (int*)ws;                   ws += 256 * 4;
    // fixed-capacity buckets overlay packed2 (dead until proj2b writes it)
    unsigned* bktK = (unsigned*)packed2;                         // nPartH*CAPK*4  (~11.2 MB)
    uint2v*   bktU = (uint2v*)(bktK + (size_t)nPartH * CAPK);    // nPartU*CAPU*8  (~11.2 MB)

    float* e_res = (float*)d_out;
    float* u_res = e_res + (size_t)n_ent * EMB;

    // ---- CSR build: fixed-capacity bucket sort (no global hist, no scans) ----
    hipMemsetAsync(pdK, 0, 512 * 4, stream);
    k1_bucket_proj<<<NBK + NBU + P3_PROJ, 256, 0, stream>>>(
        head, tail, edge_type, E, pdK, bktK,
        iu, ii, inter_w, EI, pdU, bktU,
        entity_emb, W_Q, packed, e_bf, n_ent, nPartH, nPartU);
    k2_sort<<<nPartH + nPartU, 256, 0, stream>>>(
        bktK, pdK, off_h, col_h, n_ent, nPartH, E,
        bktU, pdU, off_u, col_ui, n_usr, nPartU, EI);

    const int kgBlocks = (n_ent + 3) / 4;
    const int uiBlocks = (n_usr + 3) / 4;
    const int totalBlocks = kgBlocks + uiBlocks;

    // ---- hop 1 (KG table = packed, UI table = e_bf; emits enorm) ----
    agg_fused_kernel<true><<<totalBlocks, 256, 0, stream>>>(
        packed, e_bf, enorm, rel_emb, off_h, col_h, off_u, col_ui,
        entity_emb, e_res, n_ent, user_emb, u_res, n_usr, kgBlocks, totalBlocks);

    // ---- hop-2 proj from bf16 norm rows ----
    proj2b_kernel<<<PROJ2_BLOCKS, 256, 0, stream>>>(enorm, W_Q, packed2, n_ent);

    // ---- hop 2 (KG table = packed2, UI table = enorm) ----
    agg_fused_kernel<false><<<totalBlocks, 256, 0, stream>>>(
        packed2, enorm, nullptr, rel_emb, off_h, col_h, off_u, col_ui,
        nullptr, e_res, n_ent, nullptr, u_res, n_usr, kgBlocks, totalBlocks);
}